// Round 3
// baseline (881.025 us; speedup 1.0000x reference)
//
#include <hip/hip_runtime.h>
#include <hip/hip_bf16.h>
#include <hip/hip_fp16.h>
#include <stdint.h>

// C=1024, K=64, H=1024. u_hat = x @ W^T as GEMM [65536,1024]x[1024,1024]^T,
// split-bf16 (hi/lo) 3-product MFMA for ~fp32 accuracy; u_hat stored fp16.
// Then 3 routing iterations, u_hat[c] register-resident per block.

typedef __attribute__((ext_vector_type(8))) short bf16x8;
typedef __attribute__((ext_vector_type(4))) float f32x4;

__device__ __forceinline__ unsigned short f2bf(float f) {
    __hip_bfloat16 h = __float2bfloat16(f);   // RNE
    return *reinterpret_cast<unsigned short*>(&h);
}
__device__ __forceinline__ float bf2f(unsigned short u) {
    unsigned int x = ((unsigned int)u) << 16;
    return __uint_as_float(x);
}

// ---------------- W fp32 -> bf16 hi + bf16 lo ----------------
__global__ void wconv_kernel(const float* __restrict__ W,
                             unsigned short* __restrict__ Wh,
                             unsigned short* __restrict__ Wl) {
    int i = blockIdx.x * blockDim.x + threadIdx.x;   // 262144 float4s
    float4 v = reinterpret_cast<const float4*>(W)[i];
    ushort4 h, l;
    h.x = f2bf(v.x); l.x = f2bf(v.x - bf2f(h.x));
    h.y = f2bf(v.y); l.y = f2bf(v.y - bf2f(h.y));
    h.z = f2bf(v.z); l.z = f2bf(v.z - bf2f(h.z));
    h.w = f2bf(v.w); l.w = f2bf(v.w - bf2f(h.w));
    reinterpret_cast<ushort4*>(Wh)[i] = h;
    reinterpret_cast<ushort4*>(Wl)[i] = l;
}

// ---------------- GEMM: split-bf16, 128x128 tile, BK=64, 4 waves ----------------
__global__ __launch_bounds__(256, 2) void gemm_kernel(const float* __restrict__ A,
                                                      const unsigned short* __restrict__ Bh,
                                                      const unsigned short* __restrict__ Bl,
                                                      __half* __restrict__ U) {
    __shared__ __align__(16) unsigned short AsH[128 * 64];
    __shared__ __align__(16) unsigned short AsL[128 * 64];
    __shared__ __align__(16) unsigned short BsH[128 * 64];
    __shared__ __align__(16) unsigned short BsL[128 * 64];

    int bid = blockIdx.x;                       // 4096 blocks
    int swz = (bid & 7) * 512 + (bid >> 3);     // XCD-aware, bijective (4096 % 8 == 0)
    int bm = swz >> 3;                          // 512 row-panels
    int bn = swz & 7;                           // 8 col-panels
    int t = threadIdx.x;
    int lane = t & 63;
    int w = t >> 6;
    int wm = w >> 1, wn = w & 1;

    f32x4 acc[4][4];
#pragma unroll
    for (int i = 0; i < 4; ++i)
#pragma unroll
        for (int j = 0; j < 4; ++j) acc[i][j] = (f32x4){0.f, 0.f, 0.f, 0.f};

    const size_t arow0 = (size_t)bm * 128;

    for (int kt = 0; kt < 1024; kt += 64) {
        // stage A: 128x64 fp32 -> bf16 hi/lo. 8192 fp32 = 8 x 256 threads x 4
#pragma unroll
        for (int j = 0; j < 8; ++j) {
            int off = (j * 256 + t) * 4;
            int r = off >> 6, cc = off & 63;
            float4 v = *reinterpret_cast<const float4*>(&A[(arow0 + r) * 1024 + kt + cc]);
            ushort4 h, l;
            h.x = f2bf(v.x); l.x = f2bf(v.x - bf2f(h.x));
            h.y = f2bf(v.y); l.y = f2bf(v.y - bf2f(h.y));
            h.z = f2bf(v.z); l.z = f2bf(v.z - bf2f(h.z));
            h.w = f2bf(v.w); l.w = f2bf(v.w - bf2f(h.w));
            *reinterpret_cast<ushort4*>(&AsH[r * 64 + cc]) = h;
            *reinterpret_cast<ushort4*>(&AsL[r * 64 + cc]) = l;
        }
        // stage B hi/lo: 128x64 bf16 each. 8192 ushorts = 4 x 256 x 8
#pragma unroll
        for (int j = 0; j < 4; ++j) {
            int off = (j * 256 + t) * 8;
            int r = off >> 6, cc = off & 63;
            size_t g = ((size_t)(bn * 128 + r)) * 1024 + kt + cc;
            *reinterpret_cast<uint4*>(&BsH[r * 64 + cc]) = *reinterpret_cast<const uint4*>(&Bh[g]);
            *reinterpret_cast<uint4*>(&BsL[r * 64 + cc]) = *reinterpret_cast<const uint4*>(&Bl[g]);
        }
        __syncthreads();
#pragma unroll
        for (int kk = 0; kk < 2; ++kk) {
            int krow = kk * 32 + (lane >> 4) * 8;
            bf16x8 ah[4], al[4], bh[4], bl[4];
#pragma unroll
            for (int i = 0; i < 4; ++i) {
                int ar = (wm * 64 + i * 16 + (lane & 15)) * 64 + krow;
                ah[i] = *reinterpret_cast<const bf16x8*>(&AsH[ar]);
                al[i] = *reinterpret_cast<const bf16x8*>(&AsL[ar]);
                int br = (wn * 64 + i * 16 + (lane & 15)) * 64 + krow;
                bh[i] = *reinterpret_cast<const bf16x8*>(&BsH[br]);
                bl[i] = *reinterpret_cast<const bf16x8*>(&BsL[br]);
            }
#pragma unroll
            for (int i = 0; i < 4; ++i)
#pragma unroll
                for (int j = 0; j < 4; ++j) {
                    acc[i][j] = __builtin_amdgcn_mfma_f32_16x16x32_bf16(ah[i], bh[j], acc[i][j], 0, 0, 0);
                    acc[i][j] = __builtin_amdgcn_mfma_f32_16x16x32_bf16(ah[i], bl[j], acc[i][j], 0, 0, 0);
                    acc[i][j] = __builtin_amdgcn_mfma_f32_16x16x32_bf16(al[i], bh[j], acc[i][j], 0, 0, 0);
                }
        }
        __syncthreads();
    }

    // epilogue: C/D layout col=lane&15, row=(lane>>4)*4+reg (m89-verified)
    int c0 = bn * 128 + wn * 64 + (lane & 15);
    int r0 = bm * 128 + wm * 64 + (lane >> 4) * 4;
#pragma unroll
    for (int i = 0; i < 4; ++i)
#pragma unroll
        for (int j = 0; j < 4; ++j)
#pragma unroll
            for (int rr = 0; rr < 4; ++rr) {
                size_t row = (size_t)(r0 + i * 16 + rr);
                size_t col = (size_t)(c0 + j * 16);
                U[row * 1024 + col] = __float2half(acc[i][j][rr]);
            }
}

// ---------------- routing: 1 block per c, u_hat[c] (fp16) register-resident ----------------
__global__ __launch_bounds__(512) void route_kernel(const __half* __restrict__ U,
                                                    float* __restrict__ out) {
    __shared__ float b_s[64];
    __shared__ float d_s[64];
    __shared__ float red_s[8];
    __shared__ float bp_s[64 * 8];
    __shared__ float scale_s;

    int c = blockIdx.x;
    int t = threadIdx.x;
    int lane = t & 63, w = t >> 6;
    const __half* src = U + (size_t)c * (64 * 1024);

    __half2 u_r[64];                           // thread t owns h=2t, 2t+1
#pragma unroll
    for (int k = 0; k < 64; ++k)
        u_r[k] = *reinterpret_cast<const __half2*>(&src[k * 1024 + 2 * t]);

    if (t < 64) b_s[t] = 0.0f;
    __syncthreads();

    float c0 = 0.f, c1 = 0.f;
    for (int it = 0; it < 3; ++it) {
        // softmax over K=64 (wave 0)
        if (t < 64) {
            float v = b_s[t];
            float m = v;
#pragma unroll
            for (int s = 32; s > 0; s >>= 1) m = fmaxf(m, __shfl_xor(m, s));
            float e = expf(v - m);
            float sum = e;
#pragma unroll
            for (int s = 32; s > 0; s >>= 1) sum += __shfl_xor(sum, s);
            d_s[t] = e / sum;
        }
        __syncthreads();

        // c_hat = sum_k d[k] * u_hat[k,h]
        float ch0 = 0.f, ch1 = 0.f;
#pragma unroll
        for (int k = 0; k < 64; ++k) {
            float dk = d_s[k];
            float2 uv = __half22float2(u_r[k]);
            ch0 = fmaf(dk, uv.x, ch0);
            ch1 = fmaf(dk, uv.y, ch1);
        }

        // squared norm over H (block reduction)
        float p = ch0 * ch0 + ch1 * ch1;
#pragma unroll
        for (int s = 32; s > 0; s >>= 1) p += __shfl_xor(p, s);
        if (lane == 0) red_s[w] = p;
        __syncthreads();
        if (t == 0) {
            float nrm = 0.f;
#pragma unroll
            for (int i = 0; i < 8; ++i) nrm += red_s[i];
            scale_s = sqrtf(nrm) / (1.0f + nrm);   // squash scale
        }
        __syncthreads();
        float sc = scale_s;
        c0 = sc * ch0;
        c1 = sc * ch1;
        if (it == 2) break;

        // b[k] += sum_h u_hat[k,h] * c[h]
#pragma unroll
        for (int k = 0; k < 64; ++k) {
            float2 uv = __half22float2(u_r[k]);
            float s = fmaf(c0, uv.x, c1 * uv.y);
#pragma unroll
            for (int sh = 32; sh > 0; sh >>= 1) s += __shfl_xor(s, sh);
            if (lane == 0) bp_s[k * 8 + w] = s;
        }
        __syncthreads();
        if (t < 64) {
            float a2 = 0.f;
#pragma unroll
            for (int i = 0; i < 8; ++i) a2 += bp_s[t * 8 + i];
            b_s[t] += a2;
        }
        __syncthreads();
    }

    float2 o2; o2.x = c0; o2.y = c1;
    *reinterpret_cast<float2*>(&out[(size_t)c * 1024 + 2 * t]) = o2;
}

extern "C" void kernel_launch(void* const* d_in, const int* in_sizes, int n_in,
                              void* d_out, int out_size, void* d_ws, size_t ws_size,
                              hipStream_t stream) {
    const float* x = (const float*)d_in[0];        // [1024,64,1024] fp32
    const float* W = (const float*)d_in[1];        // [1024,1024] fp32
    float* out = (float*)d_out;                    // [1024,1024] fp32

    char* ws = (char*)d_ws;
    unsigned short* Wh = (unsigned short*)ws;                        // 2 MB
    unsigned short* Wl = (unsigned short*)(ws + 2u * 1024 * 1024);   // 2 MB
    __half* U = (__half*)(ws + 4u * 1024 * 1024);                    // 128 MB fp16

    wconv_kernel<<<1024, 256, 0, stream>>>(W, Wh, Wl);
    gemm_kernel<<<4096, 256, 0, stream>>>(x, Wh, Wl, U);
    route_kernel<<<1024, 512, 0, stream>>>(U, out);
}

// Round 5
// 563.211 us; speedup vs baseline: 1.5643x; 1.5643x over previous
//
#include <hip/hip_runtime.h>
#include <hip/hip_bf16.h>
#include <hip/hip_fp16.h>
#include <stdint.h>

// C=1024, K=64, H=1024. u_hat = x @ W^T as GEMM [65536,1024]x[1024,1024]^T.
// Pure-fp16 MFMA (calibrated error ~1.2e-3 < 2.99e-3 threshold; R2/R3 anchor).
// u_hat stored fp16. 3 routing iterations, u_hat[c] register-resident.

typedef _Float16 f16x8 __attribute__((ext_vector_type(8)));
typedef __attribute__((ext_vector_type(4))) float f32x4;

// ---------------- W fp32 -> fp16 ----------------
__global__ void wconv_kernel(const float* __restrict__ W, __half* __restrict__ Wh) {
    int i = blockIdx.x * blockDim.x + threadIdx.x;   // 262144 float4s
    float4 v = reinterpret_cast<const float4*>(W)[i];
    __half h0 = __float2half(v.x), h1 = __float2half(v.y);
    __half h2 = __float2half(v.z), h3 = __float2half(v.w);
    ushort4 o;
    o.x = *(unsigned short*)&h0; o.y = *(unsigned short*)&h1;
    o.z = *(unsigned short*)&h2; o.w = *(unsigned short*)&h3;
    reinterpret_cast<ushort4*>(Wh)[i] = o;
}

// ---------------- GEMM: fp16, 128x128 tile, BK=64, 4 waves (2x2) ----------------
__global__ __launch_bounds__(256, 2) void gemm_kernel(const float* __restrict__ A,
                                                      const __half* __restrict__ B,
                                                      __half* __restrict__ U) {
    __shared__ __align__(16) __half As[128 * 64];
    __shared__ __align__(16) __half Bs[128 * 64];

    int bid = blockIdx.x;                       // 4096 blocks
    int swz = (bid & 7) * 512 + (bid >> 3);     // XCD-aware, bijective (4096 % 8 == 0)
    int bm = swz >> 3;                          // 512 row-panels
    int bn = swz & 7;                           // 8 col-panels
    int t = threadIdx.x;
    int lane = t & 63;
    int w = t >> 6;
    int wm = w >> 1, wn = w & 1;

    f32x4 acc[4][4];
#pragma unroll
    for (int i = 0; i < 4; ++i)
#pragma unroll
        for (int j = 0; j < 4; ++j) acc[i][j] = (f32x4){0.f, 0.f, 0.f, 0.f};

    const size_t arow0 = (size_t)bm * 128;

    for (int kt = 0; kt < 1024; kt += 64) {
        // stage A: 128x64 fp32 -> fp16. 8192 fp32 = 8 iters x 256 threads x 4
#pragma unroll
        for (int j = 0; j < 8; ++j) {
            int off = (j * 256 + t) * 4;
            int r = off >> 6, cc = off & 63;
            float4 v = *reinterpret_cast<const float4*>(&A[(arow0 + r) * 1024 + kt + cc]);
            __half h0 = __float2half(v.x), h1 = __float2half(v.y);
            __half h2 = __float2half(v.z), h3 = __float2half(v.w);
            ushort4 o;
            o.x = *(unsigned short*)&h0; o.y = *(unsigned short*)&h1;
            o.z = *(unsigned short*)&h2; o.w = *(unsigned short*)&h3;
            *reinterpret_cast<ushort4*>(&As[r * 64 + cc]) = o;
        }
        // stage B: 128x64 fp16. 8192 halfs = 4 iters x 256 threads x 8
#pragma unroll
        for (int j = 0; j < 4; ++j) {
            int off = (j * 256 + t) * 8;
            int r = off >> 6, cc = off & 63;
            uint4 v = *reinterpret_cast<const uint4*>(&B[((size_t)(bn * 128 + r)) * 1024 + kt + cc]);
            *reinterpret_cast<uint4*>(&Bs[r * 64 + cc]) = v;
        }
        __syncthreads();
#pragma unroll
        for (int kk = 0; kk < 2; ++kk) {
            int krow = kk * 32 + (lane >> 4) * 8;
            f16x8 af[4], bfv[4];
#pragma unroll
            for (int i = 0; i < 4; ++i) {
                af[i]  = *reinterpret_cast<const f16x8*>(&As[(wm * 64 + i * 16 + (lane & 15)) * 64 + krow]);
                bfv[i] = *reinterpret_cast<const f16x8*>(&Bs[(wn * 64 + i * 16 + (lane & 15)) * 64 + krow]);
            }
#pragma unroll
            for (int i = 0; i < 4; ++i)
#pragma unroll
                for (int j = 0; j < 4; ++j)
                    acc[i][j] = __builtin_amdgcn_mfma_f32_16x16x32_f16(af[i], bfv[j], acc[i][j], 0, 0, 0);
        }
        __syncthreads();
    }

    // epilogue: C/D layout col=lane&15, row=(lane>>4)*4+reg (m89-verified, dtype-indep)
    int c0 = bn * 128 + wn * 64 + (lane & 15);
    int r0 = bm * 128 + wm * 64 + (lane >> 4) * 4;
#pragma unroll
    for (int i = 0; i < 4; ++i)
#pragma unroll
        for (int j = 0; j < 4; ++j)
#pragma unroll
            for (int rr = 0; rr < 4; ++rr) {
                size_t row = (size_t)(r0 + i * 16 + rr);
                size_t col = (size_t)(c0 + j * 16);
                U[row * 1024 + col] = __float2half(acc[i][j][rr]);
            }
}

// ---------------- routing: 1 block per c, u_hat[c] (fp16) register-resident ----------------
// 512 threads; thread t owns h=2t,2t+1. b-update uses a reduce-scatter butterfly:
// lane l ends holding the wave-partial for k=l (63 shuffles vs 384 for per-k reduce).
__global__ __launch_bounds__(512, 1) void route_kernel(const __half* __restrict__ U,
                                                       float* __restrict__ out) {
    __shared__ float b_s[64];
    __shared__ float d_s[64];
    __shared__ float red_s[8];
    __shared__ float bp_s[8 * 64];
    __shared__ float scale_s;

    int c = blockIdx.x;
    int t = threadIdx.x;
    int lane = t & 63, w = t >> 6;
    const __half* src = U + (size_t)c * (64 * 1024);

    __half2 u_r[64];
#pragma unroll
    for (int k = 0; k < 64; ++k)
        u_r[k] = *reinterpret_cast<const __half2*>(&src[k * 1024 + 2 * t]);

    if (t < 64) b_s[t] = 0.0f;
    __syncthreads();

    float c0 = 0.f, c1 = 0.f;
    for (int it = 0; it < 3; ++it) {
        // softmax over K=64 (wave 0)
        if (t < 64) {
            float v = b_s[t];
            float m = v;
#pragma unroll
            for (int s = 32; s > 0; s >>= 1) m = fmaxf(m, __shfl_xor(m, s));
            float e = expf(v - m);
            float sum = e;
#pragma unroll
            for (int s = 32; s > 0; s >>= 1) sum += __shfl_xor(sum, s);
            d_s[t] = e / sum;
        }
        __syncthreads();

        // c_hat = sum_k d[k] * u_hat[k,h]  (thread-local in h)
        float ch0 = 0.f, ch1 = 0.f;
#pragma unroll
        for (int k = 0; k < 64; ++k) {
            float dk = d_s[k];
            float2 uv = __half22float2(u_r[k]);
            ch0 = fmaf(dk, uv.x, ch0);
            ch1 = fmaf(dk, uv.y, ch1);
        }

        // squared norm over H (block reduction)
        float p = ch0 * ch0 + ch1 * ch1;
#pragma unroll
        for (int s = 32; s > 0; s >>= 1) p += __shfl_xor(p, s);
        if (lane == 0) red_s[w] = p;
        __syncthreads();
        if (t == 0) {
            float nrm = 0.f;
#pragma unroll
            for (int i = 0; i < 8; ++i) nrm += red_s[i];
            scale_s = sqrtf(nrm) / (1.0f + nrm);   // squash scale
        }
        __syncthreads();
        float sc = scale_s;
        c0 = sc * ch0;
        c1 = sc * ch1;
        if (it == 2) break;

        // b[k] += sum_h u_hat[k,h]*c[h] : butterfly reduce-scatter over the wave
        float cur[64];
#pragma unroll
        for (int k = 0; k < 64; ++k) {
            float2 uv = __half22float2(u_r[k]);
            cur[k] = fmaf(c0, uv.x, c1 * uv.y);
        }
#pragma unroll
        for (int j = 5; j >= 0; --j) {
            const int s = 1 << j;
            const bool bsel = (lane >> j) & 1;
#pragma unroll
            for (int i = 0; i < (1 << j); ++i) {
                // keep half with bit_j(k)==bit_j(lane); send the other (static indices + cndmask)
                float keep = bsel ? cur[s + i] : cur[i];
                float send = bsel ? cur[i] : cur[s + i];
                cur[i] = keep + __shfl_xor(send, s);
            }
        }
        bp_s[w * 64 + lane] = cur[0];           // wave-partial for k = lane
        __syncthreads();
        if (t < 64) {
            float a2 = 0.f;
#pragma unroll
            for (int i = 0; i < 8; ++i) a2 += bp_s[i * 64 + t];
            b_s[t] += a2;
        }
        __syncthreads();
    }

    float2 o2; o2.x = c0; o2.y = c1;
    *reinterpret_cast<float2*>(&out[(size_t)c * 1024 + 2 * t]) = o2;
}

extern "C" void kernel_launch(void* const* d_in, const int* in_sizes, int n_in,
                              void* d_out, int out_size, void* d_ws, size_t ws_size,
                              hipStream_t stream) {
    const float* x = (const float*)d_in[0];        // [1024,64,1024] fp32
    const float* W = (const float*)d_in[1];        // [1024,1024] fp32
    float* out = (float*)d_out;                    // [1024,1024] fp32

    char* ws = (char*)d_ws;
    __half* Wh = (__half*)ws;                      // 2 MB
    __half* U  = (__half*)(ws + 2u * 1024 * 1024); // 128 MB fp16

    wconv_kernel<<<1024, 256, 0, stream>>>(W, Wh);
    gemm_kernel<<<4096, 256, 0, stream>>>(x, Wh, U);
    route_kernel<<<1024, 512, 0, stream>>>(U, out);
}